// Round 11
// baseline (2616.878 us; speedup 1.0000x reference)
//
#include <hip/hip_runtime.h>
#include <hip/hip_bf16.h>
#include <math.h>

// B=256, T=128; text 768->256, audio 74->128, video 35->128
// z[b][t][512] = [audio(128) | video(128) | text(256)]  (bf16)

typedef __attribute__((ext_vector_type(8))) short short8;   // 8 bf16
typedef __attribute__((ext_vector_type(4))) float f32x4;

__device__ __forceinline__ float sigm(float x) { return 1.0f / (1.0f + __expf(-x)); }
__device__ __forceinline__ float tanh_(float x) {
    float ax = fabsf(x);
    float e  = __expf(-2.0f * ax);
    float t  = (1.0f - e) / (1.0f + e);
    return copysignf(t, x);
}
__device__ __forceinline__ ushort f2bf(float x) {
    __hip_bfloat16 h = __float2bfloat16(x);
    return *reinterpret_cast<ushort*>(&h);
}
__device__ __forceinline__ float bf2f(ushort u) { return __uint_as_float(((unsigned)u) << 16); }

__device__ __forceinline__ void gl_lds16(const void* g, void* l) {
    __builtin_amdgcn_global_load_lds(
        (const __attribute__((address_space(1))) unsigned int*)g,
        (__attribute__((address_space(3))) unsigned int*)l, 16, 0, 0);
}

#define BARRIER_LIGHT() \
    do { asm volatile("s_waitcnt lgkmcnt(0)" ::: "memory"); \
         __builtin_amdgcn_s_barrier(); \
         asm volatile("" ::: "memory"); } while (0)

// ---------------------------------------------------------------------------
// MFMA GEMM: gates = A_f32[M,K] * W_f32[N,K]^T + bias -> bf16 fragment layouts.
// text (N==1024): pos-split layout for lstm_mfma6 (FIXED strides: 65536/16384):
//   idx = (bg*128+t)*65536 + ps*16384 + w*2048 + grt*1024 + bt*256 + np*16 + k8*4 + g
// a/v (N==512): unchanged v5 layout.
// ---------------------------------------------------------------------------
__global__ __launch_bounds__(256) void gemm_mfma(
    const float* __restrict__ A, const float* __restrict__ W,
    const float* __restrict__ bias, ushort* __restrict__ C,
    int M, int N, int K)
{
    constexpr int STR = 40;
    __shared__ ushort As[128 * STR];
    __shared__ ushort Ws[128 * STR];

    const int tid  = threadIdx.x;
    const int lane = tid & 63;
    const int wave = tid >> 6;
    const int bm   = blockIdx.y * 128;
    const int bn   = blockIdx.x * 128;
    const int m0   = (wave >> 1) * 64;
    const int n0   = (wave & 1) * 64;
    const int row  = tid >> 1;
    const int kseg = (tid & 1) * 16;
    const int fr   = lane & 15;
    const int fk   = (lane >> 4) * 8;

    f32x4 acc[4][4];
#pragma unroll
    for (int i = 0; i < 4; ++i)
#pragma unroll
        for (int j = 0; j < 4; ++j) acc[i][j] = (f32x4)(0.f);

    const bool kmul4 = (K & 3) == 0;

    for (int k0 = 0; k0 < K; k0 += 32) {
        {
            const float* ap = A + (size_t)(bm + row) * K + k0 + kseg;
            if (kmul4 && (k0 + kseg + 16) <= K) {
                float4 v0 = *(const float4*)ap;
                float4 v1 = *(const float4*)(ap + 4);
                float4 v2 = *(const float4*)(ap + 8);
                float4 v3 = *(const float4*)(ap + 12);
                short8 o0, o1;
                o0[0]=f2bf(v0.x); o0[1]=f2bf(v0.y); o0[2]=f2bf(v0.z); o0[3]=f2bf(v0.w);
                o0[4]=f2bf(v1.x); o0[5]=f2bf(v1.y); o0[6]=f2bf(v1.z); o0[7]=f2bf(v1.w);
                o1[0]=f2bf(v2.x); o1[1]=f2bf(v2.y); o1[2]=f2bf(v2.z); o1[3]=f2bf(v2.w);
                o1[4]=f2bf(v3.x); o1[5]=f2bf(v3.y); o1[6]=f2bf(v3.z); o1[7]=f2bf(v3.w);
                *(short8*)&As[row * STR + kseg]     = o0;
                *(short8*)&As[row * STR + kseg + 8] = o1;
            } else {
#pragma unroll
                for (int j = 0; j < 16; ++j) {
                    int kk = k0 + kseg + j;
                    As[row * STR + kseg + j] = (kk < K) ? f2bf(ap[j]) : (ushort)0;
                }
            }
        }
        {
            const float* wp = W + (size_t)(bn + row) * K + k0 + kseg;
            if (kmul4 && (k0 + kseg + 16) <= K) {
                float4 v0 = *(const float4*)wp;
                float4 v1 = *(const float4*)(wp + 4);
                float4 v2 = *(const float4*)(wp + 8);
                float4 v3 = *(const float4*)(wp + 12);
                short8 o0, o1;
                o0[0]=f2bf(v0.x); o0[1]=f2bf(v0.y); o0[2]=f2bf(v0.z); o0[3]=f2bf(v0.w);
                o0[4]=f2bf(v1.x); o0[5]=f2bf(v1.y); o0[6]=f2bf(v1.z); o0[7]=f2bf(v1.w);
                o1[0]=f2bf(v2.x); o1[1]=f2bf(v2.y); o1[2]=f2bf(v2.z); o1[3]=f2bf(v2.w);
                o1[4]=f2bf(v3.x); o1[5]=f2bf(v3.y); o1[6]=f2bf(v3.z); o1[7]=f2bf(v3.w);
                *(short8*)&Ws[row * STR + kseg]     = o0;
                *(short8*)&Ws[row * STR + kseg + 8] = o1;
            } else {
#pragma unroll
                for (int j = 0; j < 16; ++j) {
                    int kk = k0 + kseg + j;
                    Ws[row * STR + kseg + j] = (kk < K) ? f2bf(wp[j]) : (ushort)0;
                }
            }
        }
        __syncthreads();

        short8 af[4], wf[4];
#pragma unroll
        for (int mi = 0; mi < 4; ++mi)
            af[mi] = *(const short8*)&As[(m0 + mi * 16 + fr) * STR + fk];
#pragma unroll
        for (int ni = 0; ni < 4; ++ni)
            wf[ni] = *(const short8*)&Ws[(n0 + ni * 16 + fr) * STR + fk];
#pragma unroll
        for (int mi = 0; mi < 4; ++mi)
#pragma unroll
            for (int ni = 0; ni < 4; ++ni)
                acc[mi][ni] = __builtin_amdgcn_mfma_f32_16x16x32_bf16(
                    af[mi], wf[ni], acc[mi][ni], 0, 0, 0);
        __syncthreads();
    }

#pragma unroll
    for (int ni = 0; ni < 4; ++ni) {
        const int col = bn + n0 + ni * 16 + fr;
        const float bb = bias[col];
#pragma unroll
        for (int mi = 0; mi < 4; ++mi)
#pragma unroll
            for (int q = 0; q < 4; ++q) {
                int r  = bm + m0 + mi * 16 + (lane >> 4) * 4 + q;
                int b  = r >> 7, t = r & 127;
                size_t idx;
                if (N == 1024) {
                    int g = col >> 8, pos = col & 255;
                    int psx = pos >> 6, p = pos & 63;
                    int wq = p >> 3, grtx = (p >> 2) & 1, k8x = p & 3;
                    int bgx = b >> 6, bl = b & 63, btx = bl >> 4, npx = bl & 15;
                    idx = (size_t)(bgx * 128 + t) * 65536 + (size_t)psx * 16384
                        + wq * 2048 + grtx * 1024 + btx * 256 + npx * 16 + k8x * 4 + g;
                } else {
                    int g = col >> 7, wq = (col >> 4) & 7, pl = col & 15;
                    idx = ((((size_t)(b >> 4) * 128 + t) * 8 + wq) * 4 + g) * 256
                        + (size_t)(b & 15) * 16 + pl;
                }
                C[idx] = f2bf(acc[mi][ni][q] + bb);
            }
    }
}

// ---------------------------------------------------------------------------
// Pack W_hh. TEXT: per ps-slice [ps][r(256)][k(256)], r = p*4+g, additive
// 16B-unit swizzle phys = (u + 4r) & 31. A/V: v5 fragment-major layout.
// ---------------------------------------------------------------------------
__global__ void wfrag_pack(const float* __restrict__ Wt, const float* __restrict__ Wa,
                           const float* __restrict__ Wv, ushort* __restrict__ WFt,
                           ushort* __restrict__ WFa, ushort* __restrict__ WFv)
{
    int idx = blockIdx.x * 256 + threadIdx.x;
    if (idx < 262144) {
        int e = idx;
        int ps = e >> 16, rem = e & 65535, r = rem >> 8, kk = rem & 255;
        int g = r & 3, p = r >> 2;
        int n = g * 256 + ps * 64 + p;
        int pu = ((kk >> 3) + 4 * r) & 31;
        WFt[(size_t)ps * 65536 + r * 256 + pu * 8 + (kk & 7)] =
            f2bf(Wt[(size_t)n * 256 + kk]);
    } else if (idx < 327680) {
        int e = idx - 262144;
        int jj = e & 7, k8 = (e >> 3) & 3, n = (e >> 5) & 15;
        int g = (e >> 9) & 3, w = (e >> 11) & 7, kt = (e >> 14) & 3;
        WFa[e] = f2bf(Wa[(size_t)(g * 128 + w * 16 + n) * 128 + kt * 32 + k8 * 8 + jj]);
    } else if (idx < 393216) {
        int e = idx - 327680;
        int jj = e & 7, k8 = (e >> 3) & 3, n = (e >> 5) & 15;
        int g = (e >> 9) & 3, w = (e >> 11) & 7, kt = (e >> 14) & 3;
        WFv[e] = f2bf(Wv[(size_t)(g * 128 + w * 16 + n) * 128 + kt * 32 + k8 * 8 + jj]);
    }
}

__global__ void wf_pack(const float* __restrict__ W1, const float* __restrict__ W2,
                        ushort* __restrict__ W1b, ushort* __restrict__ W2ab,
                        ushort* __restrict__ W2bb)
{
    int idx = blockIdx.x * 256 + threadIdx.x;
    if (idx >= 1048576) return;
    int r = idx >> 9, c = idx & 511;
    W1b[idx]  = f2bf(W1[idx]);
    W2ab[idx] = f2bf(W2[(size_t)r * 1025 + 1 + c]);
    W2bb[idx] = f2bf(W2[(size_t)r * 1025 + 513 + c]);
}

__global__ void zero_flags(int* flags) {
    int i = blockIdx.x * 256 + threadIdx.x;
    if (i < 512) flags[i] = 0;
}

// ---------------------------------------------------------------------------
// LSTM v6 (xp-stride fix). TEXT: pos-split(4) x batch-split(4); W slice
// LDS-resident; h exchanged via zbuf; flag sync. A/V: v5 path.
// ---------------------------------------------------------------------------
#define AV_STEP(T, XC, XN, RP)                                                     \
    do {                                                                           \
        short8 hf[4];                                                              \
        _Pragma("unroll") for (int kt = 0; kt < 4; ++kt) {                         \
            int byt = (RP) * 4096 + np * 256 + kt * 64 + k8 * 16;                  \
            hf[kt] = *(const short8*)(hbase + (byt ^ ((np & 7) << 4)));            \
        }                                                                          \
        f32x4 acc[4];                                                              \
        _Pragma("unroll") for (int g = 0; g < 4; ++g) acc[g] = (f32x4)(0.f);       \
        _Pragma("unroll") for (int kt = 0; kt < 4; ++kt)                           \
            _Pragma("unroll") for (int g = 0; g < 4; ++g)                          \
                acc[g] = __builtin_amdgcn_mfma_f32_16x16x32_bf16(wres[kt][g], hf[kt], acc[g], 0, 0, 0); \
        { const ushort* xrn = xbase + (size_t)(((T) + 1) & 127) * 8192;            \
          _Pragma("unroll") for (int g = 0; g < 4; ++g)                            \
              (XN)[g] = *(const uint2*)(xrn + g * 256); }                          \
        _Pragma("unroll") for (int g = 0; g < 4; ++g) {                            \
            acc[g][0] += bf2f((ushort)((XC)[g].x & 0xffffu));                      \
            acc[g][1] += bf2f((ushort)((XC)[g].x >> 16));                          \
            acc[g][2] += bf2f((ushort)((XC)[g].y & 0xffffu));                      \
            acc[g][3] += bf2f((ushort)((XC)[g].y >> 16));                          \
        }                                                                          \
        ushort hq[4];                                                              \
        _Pragma("unroll") for (int q = 0; q < 4; ++q) {                            \
            float cc = sigm(acc[1][q]) * c_st0[q] + sigm(acc[0][q]) * tanh_(acc[2][q]); \
            c_st0[q] = cc;                                                         \
            hq[q] = f2bf(sigm(acc[3][q]) * tanh_(cc));                             \
        }                                                                          \
        uint2 hw;                                                                  \
        hw.x = (uint)hq[0] | ((uint)hq[1] << 16);                                  \
        hw.y = (uint)hq[2] | ((uint)hq[3] << 16);                                  \
        {                                                                          \
            int byt = ((RP) ^ 1) * 4096 + np * 256 + w * 32 + k8 * 8;              \
            *(uint2*)(hbase + (byt ^ ((np & 7) << 4))) = hw;                       \
            *(uint2*)(zb + zrow + (size_t)(T) * 512) = hw;                         \
        }                                                                          \
        BARRIER_LIGHT();                                                           \
    } while (0)

__global__ __launch_bounds__(512) void lstm_mfma6(
    const ushort* __restrict__ xpt, const ushort* __restrict__ xpa,
    const ushort* __restrict__ xpv, const ushort* __restrict__ WFt,
    const ushort* __restrict__ WFa, const ushort* __restrict__ WFv,
    ushort* __restrict__ zb, int* __restrict__ flags)
{
    __shared__ __align__(16) char smem[131072];
    const int tid  = threadIdx.x;
    const int lane = tid & 63;
    const int w    = tid >> 6;
    const int np   = lane & 15;
    const int k8   = lane >> 4;
    const int bid  = blockIdx.x;

    if (bid < 16) {
        // ------------------------- text: H=256, K=256 -------------------------
        const int bg = bid >> 2, ps = bid & 3;
        {
            const char* wg = (const char*)WFt + (size_t)ps * 131072 + w * 16384 + lane * 16;
            char* wl = smem + w * 16384;
#pragma unroll
            for (int i = 0; i < 16; ++i) gl_lds16(wg + i * 1024, wl + i * 1024);
        }
        asm volatile("s_waitcnt vmcnt(0)" ::: "memory");
        __syncthreads();

        float c_st[2][4];
#pragma unroll
        for (int g2 = 0; g2 < 2; ++g2)
#pragma unroll
            for (int q = 0; q < 4; ++q) c_st[g2][q] = 0.f;

        const ushort* xthr = xpt + (size_t)bg * 128 * 65536 + (size_t)ps * 16384
                             + w * 2048 + np * 16 + k8 * 4;
        const ushort* zrd0 = zb + ((size_t)(bg * 64 + np) * 128) * 512 + 256 + k8 * 8;
        ushort*       zwr0 = zb + ((size_t)(bg * 64 + np) * 128) * 512 + 256
                             + ps * 64 + w * 8 + k8;
        const int w32 = w * 32;
        int* const flg = flags + bg * 128;

#pragma unroll 1
        for (int t = 0; t < 128; ++t) {
            if (t > 0) {
                if (tid == 0) {
                    while (atomicAdd(&flg[t - 1], 0) < 4) __builtin_amdgcn_s_sleep(2);
                }
                __syncthreads();
                __threadfence();   // acquire: make peers' z(t-1) visible
            }
            // xp fragments for this step
            uint2 xv[8];
            {
                const ushort* xr = xthr + (size_t)t * 65536;
#pragma unroll
                for (int grt = 0; grt < 2; ++grt)
#pragma unroll
                    for (int bt = 0; bt < 4; ++bt)
                        xv[grt * 4 + bt] = *(const uint2*)(xr + grt * 1024 + bt * 256);
            }
            f32x4 acc[2][4];
#pragma unroll
            for (int grt = 0; grt < 2; ++grt)
#pragma unroll
                for (int bt = 0; bt < 4; ++bt) acc[grt][bt] = (f32x4)(0.f);

            if (t > 0) {
                const ushort* zr = zrd0 + (size_t)(t - 1) * 512;
                short8 bA[4], bB[4];
#pragma unroll
                for (int bt = 0; bt < 4; ++bt)
                    bA[bt] = *(const short8*)(zr + (size_t)bt * 1048576);
#pragma unroll
                for (int kt = 0; kt < 8; ++kt) {
                    if (kt < 7) {
                        if ((kt & 1) == 0) {
#pragma unroll
                            for (int bt = 0; bt < 4; ++bt)
                                bB[bt] = *(const short8*)(zr + (size_t)bt * 1048576 + (kt + 1) * 32);
                        } else {
#pragma unroll
                            for (int bt = 0; bt < 4; ++bt)
                                bA[bt] = *(const short8*)(zr + (size_t)bt * 1048576 + (kt + 1) * 32);
                        }
                    }
                    const int row0 = w32 + np;
                    const int row1 = w32 + 16 + np;
                    short8 wa0 = *(const short8*)(smem + row0 * 512 +
                                    (((kt * 4 + k8 + row0 * 4) & 31) << 4));
                    short8 wa1 = *(const short8*)(smem + row1 * 512 +
                                    (((kt * 4 + k8 + row1 * 4) & 31) << 4));
                    asm volatile("s_waitcnt lgkmcnt(0)" ::: "memory");
                    __builtin_amdgcn_sched_barrier(0);
                    if (kt < 7) { asm volatile("s_waitcnt vmcnt(4)" ::: "memory"); }
                    else        { asm volatile("s_waitcnt vmcnt(0)" ::: "memory"); }
                    __builtin_amdgcn_sched_barrier(0);
                    if ((kt & 1) == 0) {
#pragma unroll
                        for (int bt = 0; bt < 4; ++bt) {
                            acc[0][bt] = __builtin_amdgcn_mfma_f32_16x16x32_bf16(wa0, bA[bt], acc[0][bt], 0, 0, 0);
                            acc[1][bt] = __builtin_amdgcn_mfma_f32_16x16x32_bf16(wa1, bA[bt], acc[1][bt], 0, 0, 0);
                        }
                    } else {
#pragma unroll
                        for (int bt = 0; bt < 4; ++bt) {
                            acc[0][bt] = __builtin_amdgcn_mfma_f32_16x16x32_bf16(wa0, bB[bt], acc[0][bt], 0, 0, 0);
                            acc[1][bt] = __builtin_amdgcn_mfma_f32_16x16x32_bf16(wa1, bB[bt], acc[1][bt], 0, 0, 0);
                        }
                    }
                }
            } else {
                asm volatile("s_waitcnt vmcnt(0)" ::: "memory");
            }

            // xp add + activations + z stores
            ushort* zw = zwr0 + (size_t)t * 512;
#pragma unroll
            for (int grt = 0; grt < 2; ++grt)
#pragma unroll
                for (int bt = 0; bt < 4; ++bt) {
                    const uint2 xq = xv[grt * 4 + bt];
                    float iv = acc[grt][bt][0] + bf2f((ushort)(xq.x & 0xffffu));
                    float fv = acc[grt][bt][1] + bf2f((ushort)(xq.x >> 16));
                    float gv = acc[grt][bt][2] + bf2f((ushort)(xq.y & 0xffffu));
                    float ov = acc[grt][bt][3] + bf2f((ushort)(xq.y >> 16));
                    float cc = sigm(fv) * c_st[grt][bt] + sigm(iv) * tanh_(gv);
                    c_st[grt][bt] = cc;
                    zw[(size_t)bt * 1048576 + grt * 4] = f2bf(sigm(ov) * tanh_(cc));
                }
            __threadfence();   // release: z(t) visible device-wide
            __syncthreads();
            if (tid == 0) atomicAdd(&flg[t], 1);
        }
    } else {
        // ----------------------- audio / video: H=128, K=128 -------------------
        char* hbase = smem;
        const bool isA = bid < 32;
        const int bt = bid - (isA ? 16 : 32);
        const ushort* xp = isA ? xpa : xpv;
        const ushort* WF = isA ? WFa : WFv;
        const int zoff = isA ? 0 : 128;

        short8 wres[4][4];
#pragma unroll
        for (int kt = 0; kt < 4; ++kt)
#pragma unroll
            for (int g = 0; g < 4; ++g)
                wres[kt][g] = *(const short8*)(WF + (size_t)((kt * 8 + w) * 4 + g) * 512 + np * 32 + k8 * 8);
        for (int i = tid; i < 2048; i += 512) ((uint*)hbase)[i] = 0u;
        float c_st0[4];
#pragma unroll
        for (int q = 0; q < 4; ++q) c_st0[q] = 0.f;
        __syncthreads();

        const ushort* xbase = xp + (size_t)bt * 1048576 + w * 1024 + np * 16 + k8 * 4;
        const size_t  zrow  = ((size_t)(bt * 16 + np) * 128) * 512 + zoff + w * 16 + k8 * 4;

        uint2 xvA[4], xvB[4];
#pragma unroll
        for (int g = 0; g < 4; ++g) xvA[g] = *(const uint2*)(xbase + g * 256);

#pragma unroll 1
        for (int t = 0; t < 128; t += 2) {
            AV_STEP(t,     xvA, xvB, 0);
            AV_STEP(t + 1, xvB, xvA, 1);
        }
    }
}

// ---------------------------------------------------------------------------
// MFMA fusion head (verified R2-R9).
// ---------------------------------------------------------------------------
__global__ __launch_bounds__(256) void fuse_mfma(
    const ushort* __restrict__ zb, const ushort* __restrict__ W1b,
    const ushort* __restrict__ W2ab, const ushort* __restrict__ W2bb,
    const float* __restrict__ b1, const float* __restrict__ b2,
    const float* __restrict__ W2, float* __restrict__ zf)
{
    constexpr int STR = 40;
    __shared__ ushort As[64 * STR];
    __shared__ ushort W1s[256 * STR];
    __shared__ ushort W2s[256 * STR];

    const int tid  = threadIdx.x;
    const int lane = tid & 63;
    const int wave = tid >> 6;
    const int b    = blockIdx.y;
    const int r0   = blockIdx.x * 256;
    const int n0w  = wave * 64;

    const int a_row  = tid >> 2;
    const int a_c8   = (tid & 3) * 8;
    const int fr_row = lane & 15;
    const int fr_k   = (lane >> 4) * 8;

    f32x4 acc1[4][4], acc2[4][4];
#pragma unroll
    for (int i = 0; i < 4; ++i)
#pragma unroll
        for (int j = 0; j < 4; ++j) {
            acc1[i][j] = (f32x4)(0.f);
            acc2[i][j] = (f32x4)(0.f);
        }

    for (int pass = 0; pass < 2; ++pass) {
        const ushort* wsrc = pass ? W2bb : W2ab;
        for (int c0 = 0; c0 < 512; c0 += 32) {
            {
                const int4 v = *(const int4*)(zb +
                    (((size_t)b * 128 + 2 * a_row + pass) * 512 + c0 + a_c8));
                *(int4*)&As[a_row * STR + a_c8] = v;
            }
            if (pass == 0) {
                const ushort* w1p = W1b + (size_t)(r0 + tid) * 512 + c0;
#pragma unroll
                for (int j = 0; j < 4; ++j)
                    *(int4*)&W1s[tid * STR + j * 8] = *(const int4*)(w1p + j * 8);
            }
            {
                const ushort* w2p = wsrc + (size_t)(r0 + tid) * 512 + c0;
#pragma unroll
                for (int j = 0; j < 4; ++j)
                    *(int4*)&W2s[tid * STR + j * 8] = *(const int4*)(w2p + j * 8);
            }
            __syncthreads();

            short8 af[4], w2f[4];
#pragma unroll
            for (int mi = 0; mi < 4; ++mi)
                af[mi] = *(const short8*)&As[(mi * 16 + fr_row) * STR + fr_k];
#pragma unroll
            for (int ni = 0; ni < 4; ++ni)
                w2f[ni] = *(const short8*)&W2s[(n0w + ni * 16 + fr_row) * STR + fr_k];

            if (pass == 0) {
                short8 w1f[4];
#pragma unroll
                for (int ni = 0; ni < 4; ++ni)
                    w1f[ni] = *(const short8*)&W1s[(n0w + ni * 16 + fr_row) * STR + fr_k];
#pragma unroll
                for (int mi = 0; mi < 4; ++mi)
#pragma unroll
                    for (int ni = 0; ni < 4; ++ni) {
                        acc1[mi][ni] = __builtin_amdgcn_mfma_f32_16x16x32_bf16(
                            af[mi], w1f[ni], acc1[mi][ni], 0, 0, 0);
                        acc2[mi][ni] = __builtin_amdgcn_mfma_f32_16x16x32_bf16(
                            af[mi], w2f[ni], acc2[mi][ni], 0, 0, 0);
                    }
            } else {
#pragma unroll
                for (int mi = 0; mi < 4; ++mi)
#pragma unroll
                    for (int ni = 0; ni < 4; ++ni)
                        acc2[mi][ni] = __builtin_amdgcn_mfma_f32_16x16x32_bf16(
                            af[mi], w2f[ni], acc2[mi][ni], 0, 0, 0);
            }
            __syncthreads();
        }
    }

#pragma unroll
    for (int ni = 0; ni < 4; ++ni) {
        const int r = r0 + n0w + ni * 16 + fr_row;
        const float bb1 = b1[r];
        const float bb2 = b2[r] + W2[(size_t)r * 1025];
        float s = 0.f;
#pragma unroll
        for (int mi = 0; mi < 4; ++mi)
#pragma unroll
            for (int q = 0; q < 4; ++q)
                s += (acc1[mi][ni][q] + bb1) * (acc2[mi][ni][q] + bb2);
        s += __shfl_xor(s, 16);
        s += __shfl_xor(s, 32);
        if ((lane >> 4) == 0)
            zf[(size_t)b * 2048 + r] = s * (1.0f / 64.0f);
    }
}

__global__ void final_out(const float* __restrict__ zf, const float* __restrict__ fw,
                          float* __restrict__ out)
{
    int idx = blockIdx.x * 256 + threadIdx.x;
    int b = idx >> 4, o = idx & 15;
    float s = 0.f;
#pragma unroll
    for (int r = 0; r < 128; ++r)
        s = fmaf(fw[r], zf[(size_t)b * 2048 + r * 16 + o], s);
    out[idx] = s;
}

extern "C" void kernel_launch(void* const* d_in, const int* in_sizes, int n_in,
                              void* d_out, int out_size, void* d_ws, size_t ws_size,
                              hipStream_t stream)
{
    const float* text_x  = (const float*)d_in[0];
    const float* audio_x = (const float*)d_in[1];
    const float* video_x = (const float*)d_in[2];
    const float* W_ih_t  = (const float*)d_in[3];
    const float* W_hh_t  = (const float*)d_in[4];
    const float* b_t     = (const float*)d_in[5];
    const float* W_ih_a  = (const float*)d_in[6];
    const float* W_hh_a  = (const float*)d_in[7];
    const float* b_a     = (const float*)d_in[8];
    const float* W_ih_v  = (const float*)d_in[9];
    const float* W_hh_v  = (const float*)d_in[10];
    const float* b_v     = (const float*)d_in[11];
    const float* W1      = (const float*)d_in[12];
    const float* b1      = (const float*)d_in[13];
    const float* W2      = (const float*)d_in[14];
    const float* b2      = (const float*)d_in[15];
    const float* fw      = (const float*)d_in[16];
    float* out = (float*)d_out;

    // workspace layout (bytes)
    char* base = (char*)d_ws;
    ushort* xpt  = (ushort*)(base);                 // 67108864
    ushort* xpa  = (ushort*)(base + 67108864);      // 33554432
    ushort* xpv  = (ushort*)(base + 100663296);     // 33554432
    ushort* zbuf = (ushort*)(base + 134217728);     // 33554432
    ushort* WFt  = (ushort*)(base + 167772160);     //   524288
    ushort* WFa  = (ushort*)(base + 168296448);     //   131072
    ushort* WFv  = (ushort*)(base + 168427520);     //   131072
    ushort* W1b  = (ushort*)(base + 168558592);     //  2097152
    ushort* W2ab = (ushort*)(base + 170655744);     //  2097152
    ushort* W2bb = (ushort*)(base + 172752896);     //  2097152
    float*  zf   = (float*)(base + 174850048);      //  2097152
    int*    flgs = (int*)(base + 176947200);        //     2048

    gemm_mfma<<<dim3(8, 256), 256, 0, stream>>>(text_x,  W_ih_t, b_t, xpt, 32768, 1024, 768);
    gemm_mfma<<<dim3(4, 256), 256, 0, stream>>>(audio_x, W_ih_a, b_a, xpa, 32768, 512, 74);
    gemm_mfma<<<dim3(4, 256), 256, 0, stream>>>(video_x, W_ih_v, b_v, xpv, 32768, 512, 35);
    wfrag_pack<<<1536, 256, 0, stream>>>(W_hh_t, W_hh_a, W_hh_v, WFt, WFa, WFv);
    wf_pack<<<4096, 256, 0, stream>>>(W1, W2, W1b, W2ab, W2bb);
    zero_flags<<<2, 256, 0, stream>>>(flgs);
    lstm_mfma6<<<48, 512, 0, stream>>>(xpt, xpa, xpv, WFt, WFa, WFv, zbuf, flgs);
    fuse_mfma<<<dim3(8, 256), 256, 0, stream>>>(zbuf, W1b, W2ab, W2bb, b1, b2, W2, zf);
    final_out<<<16, 256, 0, stream>>>(zf, fw, out);
}

// Round 12
// 1591.538 us; speedup vs baseline: 1.6442x; 1.6442x over previous
//
#include <hip/hip_runtime.h>
#include <hip/hip_bf16.h>
#include <math.h>

// B=256, T=128; text 768->256, audio 74->128, video 35->128
// z[b][t][512] = [audio(128) | video(128) | text(256)]  (bf16)
// xp buffers stored bf16 in LSTM-fragment layout (see gemm epilogue).

typedef __attribute__((ext_vector_type(8))) short short8;   // 8 bf16
typedef __attribute__((ext_vector_type(4))) float f32x4;

__device__ __forceinline__ float sigm(float x) { return 1.0f / (1.0f + __expf(-x)); }
__device__ __forceinline__ float tanh_(float x) {
    float ax = fabsf(x);
    float e  = __expf(-2.0f * ax);
    float t  = (1.0f - e) / (1.0f + e);
    return copysignf(t, x);
}
__device__ __forceinline__ ushort f2bf(float x) {
    __hip_bfloat16 h = __float2bfloat16(x);
    return *reinterpret_cast<ushort*>(&h);
}
__device__ __forceinline__ float bf2f(ushort u) { return __uint_as_float(((unsigned)u) << 16); }

__device__ __forceinline__ void gl_lds16(const void* g, void* l) {
    __builtin_amdgcn_global_load_lds(
        (const __attribute__((address_space(1))) unsigned int*)g,
        (__attribute__((address_space(3))) unsigned int*)l, 16, 0, 0);
}

#define BARRIER_LIGHT() \
    do { asm volatile("s_waitcnt lgkmcnt(0)" ::: "memory"); \
         __builtin_amdgcn_s_barrier(); \
         asm volatile("" ::: "memory"); } while (0)

// ---------------------------------------------------------------------------
// fp32 -> bf16 bulk convert (count divisible by 8).
// ---------------------------------------------------------------------------
__global__ void cvt_bf16(const float* __restrict__ src, ushort* __restrict__ dst,
                         int n8)
{
    int i = blockIdx.x * 256 + threadIdx.x;
    if (i >= n8) return;
    float4 a = ((const float4*)src)[2 * i];
    float4 b = ((const float4*)src)[2 * i + 1];
    short8 o;
    o[0] = f2bf(a.x); o[1] = f2bf(a.y); o[2] = f2bf(a.z); o[3] = f2bf(a.w);
    o[4] = f2bf(b.x); o[5] = f2bf(b.y); o[6] = f2bf(b.z); o[7] = f2bf(b.w);
    ((short8*)dst)[i] = o;
}

// ---------------------------------------------------------------------------
// MFMA GEMM, bf16 inputs: gates = A_bf16[M,K] * W_bf16[N,K]^T + bias -> bf16
// fragment layouts (identical epilogue to the R9-verified kernel):
//  text (N==1024): idx = ((((b>>4)*128+t)*8 + w)*8 + (g*2+s))*256 + (b&15)*16 + pl
//  a/v  (N==512):  idx = ((((b>>4)*128+t)*8 + w)*4 + g)*256 + (b&15)*16 + pl
// Staging is direct bf16 copies (int4) when K%8==0 and in-bounds, else guarded.
// ---------------------------------------------------------------------------
__global__ __launch_bounds__(256) void gemm_mfma_b(
    const ushort* __restrict__ A, const ushort* __restrict__ W,
    const float* __restrict__ bias, ushort* __restrict__ C,
    int M, int N, int K)
{
    constexpr int STR = 40;
    __shared__ ushort As[128 * STR];
    __shared__ ushort Ws[128 * STR];

    const int tid  = threadIdx.x;
    const int lane = tid & 63;
    const int wave = tid >> 6;
    const int bm   = blockIdx.y * 128;
    const int bn   = blockIdx.x * 128;
    const int m0   = (wave >> 1) * 64;
    const int n0   = (wave & 1) * 64;
    const int row  = tid >> 1;
    const int kseg = (tid & 1) * 16;
    const int fr   = lane & 15;
    const int fk   = (lane >> 4) * 8;

    f32x4 acc[4][4];
#pragma unroll
    for (int i = 0; i < 4; ++i)
#pragma unroll
        for (int j = 0; j < 4; ++j) acc[i][j] = (f32x4)(0.f);

    const bool kvec = (K & 7) == 0;

    for (int k0 = 0; k0 < K; k0 += 32) {
        {
            const ushort* ap = A + (size_t)(bm + row) * K + k0 + kseg;
            if (kvec && (k0 + kseg + 16) <= K) {
                *(int4*)&As[row * STR + kseg]     = *(const int4*)ap;
                *(int4*)&As[row * STR + kseg + 8] = *(const int4*)(ap + 8);
            } else {
#pragma unroll
                for (int j = 0; j < 16; ++j) {
                    int kk = k0 + kseg + j;
                    As[row * STR + kseg + j] = (kk < K) ? ap[j] : (ushort)0;
                }
            }
        }
        {
            const ushort* wp = W + (size_t)(bn + row) * K + k0 + kseg;
            if (kvec && (k0 + kseg + 16) <= K) {
                *(int4*)&Ws[row * STR + kseg]     = *(const int4*)wp;
                *(int4*)&Ws[row * STR + kseg + 8] = *(const int4*)(wp + 8);
            } else {
#pragma unroll
                for (int j = 0; j < 16; ++j) {
                    int kk = k0 + kseg + j;
                    Ws[row * STR + kseg + j] = (kk < K) ? wp[j] : (ushort)0;
                }
            }
        }
        __syncthreads();

        short8 af[4], wf[4];
#pragma unroll
        for (int mi = 0; mi < 4; ++mi)
            af[mi] = *(const short8*)&As[(m0 + mi * 16 + fr) * STR + fk];
#pragma unroll
        for (int ni = 0; ni < 4; ++ni)
            wf[ni] = *(const short8*)&Ws[(n0 + ni * 16 + fr) * STR + fk];
#pragma unroll
        for (int mi = 0; mi < 4; ++mi)
#pragma unroll
            for (int ni = 0; ni < 4; ++ni)
                acc[mi][ni] = __builtin_amdgcn_mfma_f32_16x16x32_bf16(
                    af[mi], wf[ni], acc[mi][ni], 0, 0, 0);
        __syncthreads();
    }

    // epilogue: scatter into LSTM fragment layout (R9-verified)
#pragma unroll
    for (int ni = 0; ni < 4; ++ni) {
        const int col = bn + n0 + ni * 16 + fr;
        const float bb = bias[col];
#pragma unroll
        for (int mi = 0; mi < 4; ++mi)
#pragma unroll
            for (int q = 0; q < 4; ++q) {
                int r  = bm + m0 + mi * 16 + (lane >> 4) * 4 + q;
                int b  = r >> 7, t = r & 127;
                size_t idx;
                if (N == 1024) {
                    int g = col >> 8, w = (col >> 5) & 7, s = (col >> 4) & 1, pl = col & 15;
                    idx = ((((size_t)(b >> 4) * 128 + t) * 8 + w) * 8 + (g * 2 + s)) * 256
                        + (size_t)(b & 15) * 16 + pl;
                } else {
                    int g = col >> 7, wq = (col >> 4) & 7, pl = col & 15;
                    idx = ((((size_t)(b >> 4) * 128 + t) * 8 + wq) * 4 + g) * 256
                        + (size_t)(b & 15) * 16 + pl;
                }
                C[idx] = f2bf(acc[mi][ni][q] + bb);
            }
    }
}

// ---------------------------------------------------------------------------
// Pack W_hh into bf16 fragment-major layout (R9-verified).
// TEXT: tile-internal LANE order so gl_lds16 + ds_read_b128 are linear:
//   WFt[ti*512 + k8*128 + n*8 + jj] = Wt[(g*256+w*32+s*16+n)][kt*32+k8*8+jj],
//   ti = (kt*8+w)*8 + (g*2+s)
// A/V: fragment-major for direct per-lane VGPR loads.
// ---------------------------------------------------------------------------
__global__ void wfrag_pack(const float* __restrict__ Wt, const float* __restrict__ Wa,
                           const float* __restrict__ Wv, ushort* __restrict__ WFt,
                           ushort* __restrict__ WFa, ushort* __restrict__ WFv)
{
    int idx = blockIdx.x * 256 + threadIdx.x;
    if (idx < 262144) {
        int e = idx;
        int jj = e & 7, n = (e >> 3) & 15, k8 = (e >> 7) & 3;
        int ti = e >> 9;
        int gs = ti & 7, w = (ti >> 3) & 7, kt = ti >> 6;
        int g = gs >> 1, s = gs & 1;
        WFt[e] = f2bf(Wt[(size_t)(g * 256 + w * 32 + s * 16 + n) * 256 + kt * 32 + k8 * 8 + jj]);
    } else if (idx < 327680) {
        int e = idx - 262144;
        int jj = e & 7, k8 = (e >> 3) & 3, n = (e >> 5) & 15;
        int g = (e >> 9) & 3, w = (e >> 11) & 7, kt = (e >> 14) & 3;
        WFa[e] = f2bf(Wa[(size_t)(g * 128 + w * 16 + n) * 128 + kt * 32 + k8 * 8 + jj]);
    } else if (idx < 393216) {
        int e = idx - 327680;
        int jj = e & 7, k8 = (e >> 3) & 3, n = (e >> 5) & 15;
        int g = (e >> 9) & 3, w = (e >> 11) & 7, kt = (e >> 14) & 3;
        WFv[e] = f2bf(Wv[(size_t)(g * 128 + w * 16 + n) * 128 + kt * 32 + k8 * 8 + jj]);
    }
}

// ---------------------------------------------------------------------------
// Pack W1 / W2 to bf16 for the MFMA fusion head.
// ---------------------------------------------------------------------------
__global__ void wf_pack(const float* __restrict__ W1, const float* __restrict__ W2,
                        ushort* __restrict__ W1b, ushort* __restrict__ W2ab,
                        ushort* __restrict__ W2bb)
{
    int idx = blockIdx.x * 256 + threadIdx.x;
    if (idx >= 1048576) return;
    int r = idx >> 9, c = idx & 511;
    W1b[idx]  = f2bf(W1[idx]);
    W2ab[idx] = f2bf(W2[(size_t)r * 1025 + 1 + c]);
    W2bb[idx] = f2bf(W2[(size_t)r * 1025 + 513 + c]);
}

// ---------------------------------------------------------------------------
// MFMA LSTM recurrence v5 (R9-verified, 1030 us). Text W streamed via
// global_load_lds into per-wave LDS double-buffers with counted vmcnt waits;
// A/V W VGPR-resident; h LDS double-buffer; one light barrier per step.
// ---------------------------------------------------------------------------
#define STAGE_W(KT)                                                                \
    do {                                                                           \
        const char* gs_ = (const char*)WFt + (size_t)(((KT) * 8 + w) * 8) * 1024   \
                          + lane * 16;                                             \
        char* ld_ = wbuf + ((KT) & 1) * 8192;                                      \
        _Pragma("unroll") for (int e_ = 0; e_ < 8; ++e_)                           \
            gl_lds16(gs_ + e_ * 1024, ld_ + e_ * 1024);                            \
    } while (0)

#define TEXT_STEP(T, XC, XN, RP)                                                   \
    do {                                                                           \
        f32x4 acc[8];                                                              \
        _Pragma("unroll") for (int e = 0; e < 8; ++e) acc[e] = (f32x4)(0.f);       \
        _Pragma("unroll") for (int kt = 0; kt < 8; ++kt) {                         \
            if (kt < 2) { asm volatile("s_waitcnt vmcnt(16)" ::: "memory"); }      \
            else        { asm volatile("s_waitcnt vmcnt(8)" ::: "memory"); }       \
            __builtin_amdgcn_sched_barrier(0);                                     \
            short8 wt[8];                                                          \
            _Pragma("unroll") for (int e = 0; e < 8; ++e)                          \
                wt[e] = *(const short8*)(wbuf + (kt & 1) * 8192 + e * 1024 + lane * 16); \
            short8 hfk;                                                           \
            { int byt = (RP) * 8192 + np * 512 + kt * 64 + k8 * 16;                \
              hfk = *(const short8*)(hbase + (byt ^ ((np & 7) << 4))); }           \
            asm volatile("s_waitcnt lgkmcnt(0)" ::: "memory");                     \
            __builtin_amdgcn_sched_barrier(0);                                     \
            STAGE_W((kt + 2) & 7);                                                 \
            __builtin_amdgcn_sched_barrier(0);                                     \
            _Pragma("unroll") for (int e = 0; e < 8; ++e)                          \
                acc[e] = __builtin_amdgcn_mfma_f32_16x16x32_bf16(wt[e], hfk, acc[e], 0, 0, 0); \
        }                                                                          \
        _Pragma("unroll") for (int e = 0; e < 8; ++e) {                            \
            acc[e][0] += bf2f((ushort)((XC)[e].x & 0xffffu));                      \
            acc[e][1] += bf2f((ushort)((XC)[e].x >> 16));                          \
            acc[e][2] += bf2f((ushort)((XC)[e].y & 0xffffu));                      \
            acc[e][3] += bf2f((ushort)((XC)[e].y >> 16));                          \
        }                                                                          \
        uint2 hw[2];                                                               \
        _Pragma("unroll") for (int s = 0; s < 2; ++s) {                            \
            ushort hq[4];                                                          \
            _Pragma("unroll") for (int q = 0; q < 4; ++q) {                        \
                float iv = acc[0 + s][q], fv = acc[2 + s][q];                      \
                float gv = acc[4 + s][q], ov = acc[6 + s][q];                      \
                float cc = sigm(fv) * c_st[s][q] + sigm(iv) * tanh_(gv);           \
                c_st[s][q] = cc;                                                   \
                hq[q] = f2bf(sigm(ov) * tanh_(cc));                                \
            }                                                                      \
            hw[s].x = (uint)hq[0] | ((uint)hq[1] << 16);                           \
            hw[s].y = (uint)hq[2] | ((uint)hq[3] << 16);                           \
        }                                                                          \
        __builtin_amdgcn_sched_barrier(0);                                         \
        _Pragma("unroll") for (int s = 0; s < 2; ++s) {                            \
            int byt = ((RP) ^ 1) * 8192 + np * 512 + w * 64 + s * 32 + k8 * 8;     \
            *(uint2*)(hbase + (byt ^ ((np & 7) << 4))) = hw[s];                    \
            *(uint2*)(zb + zrow + (size_t)(T) * 512 + s * 16) = hw[s];             \
        }                                                                          \
        { const ushort* xrn = xbase + (size_t)(((T) + 1) & 127) * 16384;           \
          _Pragma("unroll") for (int e = 0; e < 8; ++e)                            \
              (XN)[e] = *(const uint2*)(xrn + e * 256); }                          \
        __builtin_amdgcn_sched_barrier(0);                                         \
        BARRIER_LIGHT();                                                           \
    } while (0)

#define AV_STEP(T, XC, XN, RP)                                                     \
    do {                                                                           \
        short8 hf[4];                                                              \
        _Pragma("unroll") for (int kt = 0; kt < 4; ++kt) {                         \
            int byt = (RP) * 4096 + np * 256 + kt * 64 + k8 * 16;                  \
            hf[kt] = *(const short8*)(hbase + (byt ^ ((np & 7) << 4)));            \
        }                                                                          \
        f32x4 acc[4];                                                              \
        _Pragma("unroll") for (int g = 0; g < 4; ++g) acc[g] = (f32x4)(0.f);       \
        _Pragma("unroll") for (int kt = 0; kt < 4; ++kt)                           \
            _Pragma("unroll") for (int g = 0; g < 4; ++g)                          \
                acc[g] = __builtin_amdgcn_mfma_f32_16x16x32_bf16(wres[kt][g], hf[kt], acc[g], 0, 0, 0); \
        { const ushort* xrn = xbase + (size_t)(((T) + 1) & 127) * 8192;            \
          _Pragma("unroll") for (int g = 0; g < 4; ++g)                            \
              (XN)[g] = *(const uint2*)(xrn + g * 256); }                          \
        _Pragma("unroll") for (int g = 0; g < 4; ++g) {                            \
            acc[g][0] += bf2f((ushort)((XC)[g].x & 0xffffu));                      \
            acc[g][1] += bf2f((ushort)((XC)[g].x >> 16));                          \
            acc[g][2] += bf2f((ushort)((XC)[g].y & 0xffffu));                      \
            acc[g][3] += bf2f((ushort)((XC)[g].y >> 16));                          \
        }                                                                          \
        ushort hq[4];                                                              \
        _Pragma("unroll") for (int q = 0; q < 4; ++q) {                            \
            float cc = sigm(acc[1][q]) * c_st0[q] + sigm(acc[0][q]) * tanh_(acc[2][q]); \
            c_st0[q] = cc;                                                         \
            hq[q] = f2bf(sigm(acc[3][q]) * tanh_(cc));                             \
        }                                                                          \
        uint2 hw;                                                                  \
        hw.x = (uint)hq[0] | ((uint)hq[1] << 16);                                  \
        hw.y = (uint)hq[2] | ((uint)hq[3] << 16);                                  \
        {                                                                          \
            int byt = ((RP) ^ 1) * 4096 + np * 256 + w * 32 + k8 * 8;              \
            *(uint2*)(hbase + (byt ^ ((np & 7) << 4))) = hw;                       \
            *(uint2*)(zb + zrow + (size_t)(T) * 512) = hw;                         \
        }                                                                          \
        BARRIER_LIGHT();                                                           \
    } while (0)

__global__ __launch_bounds__(512) void lstm_mfma5(
    const ushort* __restrict__ xpt, const ushort* __restrict__ xpa,
    const ushort* __restrict__ xpv, const ushort* __restrict__ WFt,
    const ushort* __restrict__ WFa, const ushort* __restrict__ WFv,
    ushort* __restrict__ zb)
{
    __shared__ __align__(16) char smem[147456];   // 16KB h + 8 waves x 16KB W
    const int tid  = threadIdx.x;
    const int lane = tid & 63;
    const int w    = tid >> 6;
    const int np   = lane & 15;      // batch column
    const int k8   = lane >> 4;      // k-chunk / row-quad
    const int bid  = blockIdx.x;
    char* hbase = smem;
    char* wbuf  = smem + 16384 + w * 16384;

    if (bid < 16) {
        // ------------------------- text: H=256, K=256 -------------------------
        const int bt = bid;
        const ushort* xbase = xpt + (size_t)bt * 2097152 + w * 2048 + np * 16 + k8 * 4;
        const size_t  zrow  = ((size_t)(bt * 16 + np) * 128) * 512 + 256 + w * 32 + k8 * 4;

        STAGE_W(0);
        STAGE_W(1);
        uint2 xvA[8], xvB[8];
#pragma unroll
        for (int e = 0; e < 8; ++e) xvA[e] = *(const uint2*)(xbase + e * 256);

        for (int i = tid; i < 4096; i += 512) ((uint*)hbase)[i] = 0u;
        float c_st[2][4];
#pragma unroll
        for (int s = 0; s < 2; ++s)
#pragma unroll
            for (int q = 0; q < 4; ++q) c_st[s][q] = 0.f;
        __syncthreads();   // drains everything; vmcnt counting restarts clean

#pragma unroll 1
        for (int t = 0; t < 128; t += 2) {
            TEXT_STEP(t,     xvA, xvB, 0);
            TEXT_STEP(t + 1, xvB, xvA, 1);
        }
    } else {
        // ----------------------- audio / video: H=128, K=128 -------------------
        const bool isA = bid < 32;
        const int bt = bid - (isA ? 16 : 32);
        const ushort* xp = isA ? xpa : xpv;
        const ushort* WF = isA ? WFa : WFv;
        const int zoff = isA ? 0 : 128;

        short8 wres[4][4];
#pragma unroll
        for (int kt = 0; kt < 4; ++kt)
#pragma unroll
            for (int g = 0; g < 4; ++g)
                wres[kt][g] = *(const short8*)(WF + (size_t)((kt * 8 + w) * 4 + g) * 512 + np * 32 + k8 * 8);
        for (int i = tid; i < 2048; i += 512) ((uint*)hbase)[i] = 0u;
        float c_st0[4];
#pragma unroll
        for (int q = 0; q < 4; ++q) c_st0[q] = 0.f;
        __syncthreads();

        const ushort* xbase = xp + (size_t)bt * 1048576 + w * 1024 + np * 16 + k8 * 4;
        const size_t  zrow  = ((size_t)(bt * 16 + np) * 128) * 512 + zoff + w * 16 + k8 * 4;

        uint2 xvA[4], xvB[4];
#pragma unroll
        for (int g = 0; g < 4; ++g) xvA[g] = *(const uint2*)(xbase + g * 256);

#pragma unroll 1
        for (int t = 0; t < 128; t += 2) {
            AV_STEP(t,     xvA, xvB, 0);
            AV_STEP(t + 1, xvB, xvA, 1);
        }
    }
}

// ---------------------------------------------------------------------------
// MFMA fusion head (verified R2-R9).
// ---------------------------------------------------------------------------
__global__ __launch_bounds__(256) void fuse_mfma(
    const ushort* __restrict__ zb, const ushort* __restrict__ W1b,
    const ushort* __restrict__ W2ab, const ushort* __restrict__ W2bb,
    const float* __restrict__ b1, const float* __restrict__ b2,
    const float* __restrict__ W2, float* __restrict__ zf)
{
    constexpr int STR = 40;
    __shared__ ushort As[64 * STR];
    __shared__ ushort W1s[256 * STR];
    __shared__ ushort W2s[256 * STR];

    const int tid  = threadIdx.x;
    const int lane = tid & 63;
    const int wave = tid >> 6;
    const int b    = blockIdx.y;
    const int r0   = blockIdx.x * 256;
    const int n0w  = wave * 64;

    const int a_row  = tid >> 2;
    const int a_c8   = (tid & 3) * 8;
    const int fr_row = lane & 15;
    const int fr_k   = (lane >> 4) * 8;

    f32x4 acc1[4][4], acc2[4][4];
#pragma unroll
    for (int i = 0; i < 4; ++i)
#pragma unroll
        for (int j = 0; j < 4; ++j) {
            acc1[i][j] = (f32x4)(0.f);
            acc2[i][j] = (f32x4)(0.f);
        }

    for (int pass = 0; pass < 2; ++pass) {
        const ushort* wsrc = pass ? W2bb : W2ab;
        for (int c0 = 0; c0 < 512; c0 += 32) {
            {
                const int4 v = *(const int4*)(zb +
                    (((size_t)b * 128 + 2 * a_row + pass) * 512 + c0 + a_c8));
                *(int4*)&As[a_row * STR + a_c8] = v;
            }
            if (pass == 0) {
                const ushort* w1p = W1b + (size_t)(r0 + tid) * 512 + c0;
#pragma unroll
                for (int j = 0; j < 4; ++j)
                    *(int4*)&W1s[tid * STR + j * 8] = *(const int4*)(w1p + j * 8);
            }
            {
                const ushort* w2p = wsrc + (size_t)(r0 + tid) * 512 + c0;
#pragma unroll
                for (int j = 0; j < 4; ++j)
                    *(int4*)&W2s[tid * STR + j * 8] = *(const int4*)(w2p + j * 8);
            }
            __syncthreads();

            short8 af[4], w2f[4];
#pragma unroll
            for (int mi = 0; mi < 4; ++mi)
                af[mi] = *(const short8*)&As[(mi * 16 + fr_row) * STR + fr_k];
#pragma unroll
            for (int ni = 0; ni < 4; ++ni)
                w2f[ni] = *(const short8*)&W2s[(n0w + ni * 16 + fr_row) * STR + fr_k];

            if (pass == 0) {
                short8 w1f[4];
#pragma unroll
                for (int ni = 0; ni < 4; ++ni)
                    w1f[ni] = *(const short8*)&W1s[(n0w + ni * 16 + fr_row) * STR + fr_k];
#pragma unroll
                for (int mi = 0; mi < 4; ++mi)
#pragma unroll
                    for (int ni = 0; ni < 4; ++ni) {
                        acc1[mi][ni] = __builtin_amdgcn_mfma_f32_16x16x32_bf16(
                            af[mi], w1f[ni], acc1[mi][ni], 0, 0, 0);
                        acc2[mi][ni] = __builtin_amdgcn_mfma_f32_16x16x32_bf16(
                            af[mi], w2f[ni], acc2[mi][ni], 0, 0, 0);
                    }
            } else {
#pragma unroll
                for (int mi = 0; mi < 4; ++mi)
#pragma unroll
                    for (int ni = 0; ni < 4; ++ni)
                        acc2[mi][ni] = __builtin_amdgcn_mfma_f32_16x16x32_bf16(
                            af[mi], w2f[ni], acc2[mi][ni], 0, 0, 0);
            }
            __syncthreads();
        }
    }

#pragma unroll
    for (int ni = 0; ni < 4; ++ni) {
        const int r = r0 + n0w + ni * 16 + fr_row;
        const float bb1 = b1[r];
        const float bb2 = b2[r] + W2[(size_t)r * 1025];
        float s = 0.f;
#pragma unroll
        for (int mi = 0; mi < 4; ++mi)
#pragma unroll
            for (int q = 0; q < 4; ++q)
                s += (acc1[mi][ni][q] + bb1) * (acc2[mi][ni][q] + bb2);
        s += __shfl_xor(s, 16);
        s += __shfl_xor(s, 32);
        if ((lane >> 4) == 0)
            zf[(size_t)b * 2048 + r] = s * (1.0f / 64.0f);
    }
}

__global__ void final_out(const float* __restrict__ zf, const float* __restrict__ fw,
                          float* __restrict__ out)
{
    int idx = blockIdx.x * 256 + threadIdx.x;
    int b = idx >> 4, o = idx & 15;
    float s = 0.f;
#pragma unroll
    for (int r = 0; r < 128; ++r)
        s = fmaf(fw[r], zf[(size_t)b * 2048 + r * 16 + o], s);
    out[idx] = s;
}

extern "C" void kernel_launch(void* const* d_in, const int* in_sizes, int n_in,
                              void* d_out, int out_size, void* d_ws, size_t ws_size,
                              hipStream_t stream)
{
    const float* text_x  = (const float*)d_in[0];
    const float* audio_x = (const float*)d_in[1];
    const float* video_x = (const float*)d_in[2];
    const float* W_ih_t  = (const float*)d_in[3];
    const float* W_hh_t  = (const float*)d_in[4];
    const float* b_t     = (const float*)d_in[5];
    const float* W_ih_a  = (const float*)d_in[6];
    const float* W_hh_a  = (const float*)d_in[7];
    const float* b_a     = (const float*)d_in[8];
    const float* W_ih_v  = (const float*)d_in[9];
    const float* W_hh_v  = (const float*)d_in[10];
    const float* b_v     = (const float*)d_in[11];
    const float* W1      = (const float*)d_in[12];
    const float* b1      = (const float*)d_in[13];
    const float* W2      = (const float*)d_in[14];
    const float* b2      = (const float*)d_in[15];
    const float* fw      = (const float*)d_in[16];
    float* out = (float*)d_out;

    // workspace layout (bytes)
    char* base = (char*)d_ws;
    ushort* xpt  = (ushort*)(base);                 // 67108864
    ushort* xpa  = (ushort*)(base + 67108864);      // 33554432
    ushort* xpv  = (ushort*)(base + 100663296);     // 33554432
    ushort* zbuf = (ushort*)(base + 134217728);     // 33554432
    ushort* WFt  = (ushort*)(base + 167772160);     //   524288
    ushort* WFa  = (ushort*)(base + 168296448);     //   131072
    ushort* WFv  = (ushort*)(base + 168427520);     //   131072
    ushort* W1b  = (ushort*)(base + 168558592);     //  2097152
    ushort* W2ab = (ushort*)(base + 170655744);     //  2097152
    ushort* W2bb = (ushort*)(base + 172752896);     //  2097152
    float*  zf   = (float*)(base + 174850048);      //  2097152
    ushort* txb  = (ushort*)(base + 176947200);     // 50331648 (25165824 bf16)
    ushort* axb  = (ushort*)(base + 227278848);     //  4849664 (2424832)
    ushort* vxb  = (ushort*)(base + 232128512);     //  2293760 (1146880)
    ushort* wtb  = (ushort*)(base + 234422272);     //  1572864 (786432)
    ushort* wab  = (ushort*)(base + 235995136);     //    75776 (37888)
    ushort* wvb  = (ushort*)(base + 236070912);     //    35840 (17920)

    // bulk fp32 -> bf16 converts (all counts divisible by 8)
    cvt_bf16<<<(3145728 + 255) / 256, 256, 0, stream>>>(text_x,  txb, 3145728);
    cvt_bf16<<<(303104  + 255) / 256, 256, 0, stream>>>(audio_x, axb, 303104);
    cvt_bf16<<<(143360  + 255) / 256, 256, 0, stream>>>(video_x, vxb, 143360);
    cvt_bf16<<<(98304   + 255) / 256, 256, 0, stream>>>(W_ih_t,  wtb, 98304);
    cvt_bf16<<<(4736    + 255) / 256, 256, 0, stream>>>(W_ih_a,  wab, 4736);
    cvt_bf16<<<(2240    + 255) / 256, 256, 0, stream>>>(W_ih_v,  wvb, 2240);

    gemm_mfma_b<<<dim3(8, 256), 256, 0, stream>>>(txb, wtb, b_t, xpt, 32768, 1024, 768);
    gemm_mfma_b<<<dim3(4, 256), 256, 0, stream>>>(axb, wab, b_a, xpa, 32768, 512, 74);
    gemm_mfma_b<<<dim3(4, 256), 256, 0, stream>>>(vxb, wvb, b_v, xpv, 32768, 512, 35);
    wfrag_pack<<<1536, 256, 0, stream>>>(W_hh_t, W_hh_a, W_hh_v, WFt, WFa, WFv);
    wf_pack<<<4096, 256, 0, stream>>>(W1, W2, W1b, W2ab, W2bb);
    lstm_mfma5<<<48, 512, 0, stream>>>(xpt, xpa, xpv, WFt, WFa, WFv, zbuf);
    fuse_mfma<<<dim3(8, 256), 256, 0, stream>>>(zbuf, W1b, W2ab, W2bb, b1, b2, W2, zf);
    final_out<<<16, 256, 0, stream>>>(zf, fw, out);
}